// Round 7
// baseline (203.380 us; speedup 1.0000x reference)
//
#include <hip/hip_runtime.h>
#include <hip/hip_bf16.h>

typedef __attribute__((ext_vector_type(8))) short bf16x8;
typedef __attribute__((ext_vector_type(4))) float f32x4;
typedef __attribute__((ext_vector_type(4))) unsigned int u32x4;

#define NB 2
#define NS 2048
#define ND 768
#define NH 12
#define NHD 64
#define N3D 2304
#define NM (NB * NS)   // 4096 rows

__device__ __forceinline__ unsigned short f2bf(float x) {
    union { float f; unsigned u; } v; v.f = x;
    unsigned r = v.u + 0x7FFFu + ((v.u >> 16) & 1u);   // RNE
    return (unsigned short)(r >> 16);
}

__device__ __forceinline__ unsigned cvt_pk_bf16(float lo, float hi) {
    unsigned r;
    asm volatile("v_cvt_pk_bf16_f32 %0, %1, %2" : "=v"(r) : "v"(lo), "v"(hi));
    return r;   // D.bf16[0] = lo, D.bf16[1] = hi
}

// ---------------------------------------------------------------------------
// Fused prep: region A = hs f32->bf16 convert (3072 blocks);
// region B = Wqkv transpose+convert (1728 blocks);
// region C = Wout transpose+convert (576 blocks).
// ---------------------------------------------------------------------------
__device__ __forceinline__ void transp_tile(const float* __restrict__ in,
                                            unsigned short* __restrict__ out,
                                            int K, int N, int nt, int kt,
                                            float (*T)[33]) {
    const int n0 = nt * 32, k0 = kt * 32;
    const int r = threadIdx.x >> 3, c4 = (threadIdx.x & 7) * 4;
    float4 v = *reinterpret_cast<const float4*>(&in[(size_t)(k0 + r) * N + n0 + c4]);
    T[r][c4 + 0] = v.x; T[r][c4 + 1] = v.y; T[r][c4 + 2] = v.z; T[r][c4 + 3] = v.w;
    __syncthreads();
    ushort4 o;
    o.x = f2bf(T[c4 + 0][r]); o.y = f2bf(T[c4 + 1][r]);
    o.z = f2bf(T[c4 + 2][r]); o.w = f2bf(T[c4 + 3][r]);
    *reinterpret_cast<ushort4*>(&out[(size_t)(n0 + r) * K + k0 + c4]) = o;
}

__global__ __launch_bounds__(256)
void prep(const float* __restrict__ hs, unsigned short* __restrict__ hsb,
          const float* __restrict__ Wqkv, unsigned short* __restrict__ W1t,
          const float* __restrict__ Wout, unsigned short* __restrict__ W2t) {
    __shared__ float T[32][33];
    const int bid = blockIdx.x;
    if (bid < 3072) {
        const int i = (bid * 256 + threadIdx.x) * 4;
        float4 v = *reinterpret_cast<const float4*>(hs + i);
        ushort4 o;
        o.x = f2bf(v.x); o.y = f2bf(v.y); o.z = f2bf(v.z); o.w = f2bf(v.w);
        *reinterpret_cast<ushort4*>(hsb + i) = o;
    } else if (bid < 3072 + 1728) {
        const int idx = bid - 3072;                 // Wqkv: 72 n-tiles x 24 k-tiles
        transp_tile(Wqkv, W1t, ND, N3D, idx % 72, idx / 72, T);
    } else {
        const int idx = bid - 4800;                 // Wout: 24 x 24
        transp_tile(Wout, W2t, ND, ND, idx % 24, idx / 24, T);
    }
}

// ---------------------------------------------------------------------------
// V head-transpose: V [BH][S][64] bf16 -> Vt [BH][64][S] bf16.
// ---------------------------------------------------------------------------
__global__ __launch_bounds__(256)
void vtransp(const unsigned short* __restrict__ V, unsigned short* __restrict__ Vt) {
    __shared__ __align__(16) unsigned short T[64][72];
    const int bh = blockIdx.y;
    const int s0 = blockIdx.x * 64;
    const int t = threadIdx.x;
    const unsigned short* src = V + ((size_t)bh * NS + s0) * NHD;
    const int r = t >> 2, cc = (t & 3) * 16;
    *(bf16x8*)&T[r][cc]     = *(const bf16x8*)&src[r * NHD + cc];
    *(bf16x8*)&T[r][cc + 8] = *(const bf16x8*)&src[r * NHD + cc + 8];
    __syncthreads();
    unsigned short* dst = Vt + ((size_t)bh * NHD) * NS + s0;
    const int chunk = t & 7;
#pragma unroll
    for (int h = 0; h < 2; ++h) {
        const int d = (t >> 3) + h * 32;
        bf16x8 v;
#pragma unroll
        for (int e = 0; e < 8; ++e) v[e] = (short)T[chunk * 8 + e][d];
        *(bf16x8*)&dst[(size_t)d * NS + chunk * 8] = v;
    }
}

// ---------------------------------------------------------------------------
// bf16 MFMA GEMM, K=768, m97-style single-buffer.
// ---------------------------------------------------------------------------
template<int BM, int BN, int EPI>
__global__ __launch_bounds__(256)
void gemm_k768(const unsigned short* __restrict__ A,
               const unsigned short* __restrict__ Bt,
               const float* __restrict__ bias,
               unsigned short* __restrict__ Qo, unsigned short* __restrict__ Ko,
               unsigned short* __restrict__ Vo, float* __restrict__ Co) {
    __shared__ unsigned short As[BM * 64];
    __shared__ unsigned short Bs[BN * 64];
    const int t = threadIdx.x;
    const int wv = t >> 6, lane = t & 63;
    const int lr = lane & 15, lg = lane >> 4;
    const int wr = wv >> 1, wc = wv & 1;
    const int m0 = blockIdx.y * BM;
    const int n0 = blockIdx.x * BN;
    constexpr int FM = BM / 32;
    constexpr int FN = BN / 32;

    f32x4 acc[FM][FN];
#pragma unroll
    for (int i = 0; i < FM; ++i)
#pragma unroll
        for (int j = 0; j < FN; ++j) acc[i][j] = (f32x4){0.f, 0.f, 0.f, 0.f};

    const int sr = t >> 3;
    const int sb = t & 7;

    for (int ki = 0; ki < ND / 64; ++ki) {
        const int k0 = ki * 64;
        __syncthreads();                    // prev compute's LDS reads done
#pragma unroll
        for (int jj = 0; jj < BM / 32; ++jj) {
            const int row = jj * 32 + sr;
            __builtin_amdgcn_global_load_lds(
                (const void*)(A + (size_t)(m0 + row) * ND + k0 + ((sb ^ (row & 7)) * 8)),
                (void*)(As + jj * 2048 + wv * 512), 16, 0, 0);
        }
#pragma unroll
        for (int jj = 0; jj < BN / 32; ++jj) {
            const int row = jj * 32 + sr;
            __builtin_amdgcn_global_load_lds(
                (const void*)(Bt + (size_t)(n0 + row) * ND + k0 + ((sb ^ (row & 7)) * 8)),
                (void*)(Bs + jj * 2048 + wv * 512), 16, 0, 0);
        }
        __syncthreads();                    // staged tile visible
#pragma unroll
        for (int kc = 0; kc < 2; ++kc) {
            bf16x8 af[FM], bfr[FN];
#pragma unroll
            for (int mi = 0; mi < FM; ++mi) {
                const int row = wr * (BM / 2) + mi * 16 + lr;
                af[mi] = *(const bf16x8*)&As[row * 64 + (((kc * 4 + lg) ^ (row & 7)) * 8)];
            }
#pragma unroll
            for (int nj = 0; nj < FN; ++nj) {
                const int row = wc * (BN / 2) + nj * 16 + lr;
                bfr[nj] = *(const bf16x8*)&Bs[row * 64 + (((kc * 4 + lg) ^ (row & 7)) * 8)];
            }
#pragma unroll
            for (int mi = 0; mi < FM; ++mi)
#pragma unroll
                for (int nj = 0; nj < FN; ++nj)
                    acc[mi][nj] = __builtin_amdgcn_mfma_f32_16x16x32_bf16(
                        af[mi], bfr[nj], acc[mi][nj], 0, 0, 0);
        }
    }

    if (EPI == 0) {
        const int sec = n0 / ND;
#pragma unroll
        for (int mi = 0; mi < FM; ++mi) {
#pragma unroll
            for (int nj = 0; nj < FN; ++nj) {
                const int n = n0 + wc * (BN / 2) + nj * 16 + lr;
                const int rem = n - sec * ND;
                const int hh = rem >> 6, dd = rem & 63;
                const float b = bias[n];
#pragma unroll
                for (int r = 0; r < 4; ++r) {
                    const int m = m0 + wr * (BM / 2) + mi * 16 + lg * 4 + r;
                    const int bb = m >> 11, ss = m & (NS - 1);
                    const int bhh = bb * NH + hh;
                    const float v = acc[mi][nj][r] + b;
                    if (sec == 0)   // 0.125 * log2(e): attention works in exp2 domain
                        Qo[((size_t)bhh * NS + ss) * NHD + dd] = f2bf(v * 0.18033688011112042f);
                    else if (sec == 1)
                        Ko[((size_t)bhh * NS + ss) * NHD + dd] = f2bf(v);
                    else            // V coalesced; transposed later by vtransp
                        Vo[((size_t)bhh * NS + ss) * NHD + dd] = f2bf(v);
                }
            }
        }
    } else {
#pragma unroll
        for (int mi = 0; mi < FM; ++mi)
#pragma unroll
            for (int nj = 0; nj < FN; ++nj) {
                const int n = n0 + wc * (BN / 2) + nj * 16 + lr;
                const float b = bias[n];
#pragma unroll
                for (int r = 0; r < 4; ++r) {
                    const int m = m0 + wr * (BM / 2) + mi * 16 + lg * 4 + r;
                    Co[(size_t)m * ND + n] = acc[mi][nj][r] + b;
                }
            }
    }
}

// ---------------------------------------------------------------------------
// Causal flash attention v3: barrier-free, LDS-free, one wave per 32 q-rows.
// K/V read per-lane straight from L2 (XCD-pinned, 1.5 MB/XCD working set).
// K register-double-buffered (named bufs, x2 unroll); V issued before softmax
// and consumed after (~340 cy slack). Swapped-QK^T + sigma P^T pack as before,
// now with 2 q-fragments per wave. Grid 1536 one-wave blocks = 6/CU.
// ---------------------------------------------------------------------------
__global__ __launch_bounds__(64)
void attn_mfma(const unsigned short* __restrict__ Qg,
               const unsigned short* __restrict__ Kg,
               const unsigned short* __restrict__ Vtg,
               unsigned short* __restrict__ AO) {
    const int n = blockIdx.x;                 // 1536 blocks
    const int x = n & 7, ii = n >> 3;         // XCD = n%8; 192 blocks/XCD
    const int bh = ((ii >> 6) << 3) + x;      // 3 heads per XCD
    const int j = ii & 63;
    const int qb = (j < 32) ? (2 * j) : (63 - 2 * (j - 32));  // per-CU balance
    const int lane = threadIdx.x;
    const int lr = lane & 15, lg = lane >> 4;
    const int lgp = lg & 1;
    const int q0 = qb * 32;
    const size_t bhoff = (size_t)bh * (NS * NHD);
    const unsigned short* Kb = Kg + bhoff;
    const unsigned short* Vb = Vtg + bhoff;
    const int bswz = ((lg & 1) << 1) | (lg >> 1);   // kv-block sigma

    // Q B-operand frags: qB[qf][c] supplies Q[q=q0+qf*16+lr][k=c*32+lg*8+i]
    bf16x8 qB[2][2];
#pragma unroll
    for (int qf = 0; qf < 2; ++qf)
#pragma unroll
        for (int c = 0; c < 2; ++c)
            qB[qf][c] = *(const bf16x8*)(Qg + bhoff +
                (size_t)(q0 + qf * 16 + lr) * NHD + c * 32 + lg * 8);

    float m_run[2] = {-1e30f, -1e30f}, l_part[2] = {0.f, 0.f};
    f32x4 of[4][2];
#pragma unroll
    for (int f = 0; f < 4; ++f)
#pragma unroll
        for (int qf = 0; qf < 2; ++qf) of[f][qf] = (f32x4){0.f, 0.f, 0.f, 0.f};

    const int ntiles = qb / 2 + 1;

#define LOADK(KB, kv0)                                                          \
    {                                                                           \
        _Pragma("unroll")                                                       \
        for (int f = 0; f < 4; ++f)                                             \
            _Pragma("unroll")                                                   \
            for (int c = 0; c < 2; ++c)                                         \
                KB[f][c] = *(const bf16x8*)(Kb +                                \
                    (size_t)((kv0) + f * 16 + lr) * NHD + c * 32 + lg * 8);     \
    }

#define TILE_BODY(KCUR, KNEXT, kt)                                             \
    {                                                                          \
        const int kv0 = (kt) * 64;                                             \
        f32x4 sf[4][2];                                                        \
        _Pragma("unroll")                                                      \
        for (int f = 0; f < 4; ++f)                                            \
            _Pragma("unroll")                                                  \
            for (int qf = 0; qf < 2; ++qf) sf[f][qf] = (f32x4){0.f,0.f,0.f,0.f}; \
        __builtin_amdgcn_s_setprio(1);                                         \
        _Pragma("unroll")                                                      \
        for (int f = 0; f < 4; ++f)                                            \
            _Pragma("unroll")                                                  \
            for (int c = 0; c < 2; ++c)                                        \
                _Pragma("unroll")                                              \
                for (int qf = 0; qf < 2; ++qf)                                 \
                    sf[f][qf] = __builtin_amdgcn_mfma_f32_16x16x32_bf16(       \
                        KCUR[f][c], qB[qf][c], sf[f][qf], 0, 0, 0);            \
        __builtin_amdgcn_s_setprio(0);                                         \
        if ((kt) + 1 < ntiles) LOADK(KNEXT, kv0 + 64);                         \
        bf16x8 vv[4][2];                                                       \
        _Pragma("unroll")                                                      \
        for (int fA = 0; fA < 4; ++fA)                                         \
            _Pragma("unroll")                                                  \
            for (int c = 0; c < 2; ++c)                                        \
                vv[fA][c] = *(const bf16x8*)(Vb +                              \
                    (size_t)(fA * 16 + lr) * NS + kv0 + (4 * c + bswz) * 8);   \
        if ((kt) == ntiles - 1) {                                              \
            _Pragma("unroll")                                                  \
            for (int qf = 0; qf < 2; ++qf) {                                   \
                const int thr = q0 + qf * 16 + lr - kv0;                       \
                _Pragma("unroll")                                              \
                for (int f = 0; f < 4; ++f)                                    \
                    _Pragma("unroll")                                          \
                    for (int r = 0; r < 4; ++r)                                \
                        if (f * 16 + lg * 4 + r > thr) sf[f][qf][r] = -1e30f;  \
            }                                                                  \
        }                                                                      \
        bf16x8 pb[2][2];                                                       \
        _Pragma("unroll")                                                      \
        for (int qf = 0; qf < 2; ++qf) {                                       \
            float tm = -1e30f;                                                 \
            _Pragma("unroll")                                                  \
            for (int f = 0; f < 4; ++f)                                        \
                tm = fmaxf(tm, fmaxf(fmaxf(sf[f][qf][0], sf[f][qf][1]),        \
                                     fmaxf(sf[f][qf][2], sf[f][qf][3])));      \
            tm = fmaxf(tm, __shfl_xor(tm, 16));                                \
            tm = fmaxf(tm, __shfl_xor(tm, 32));                                \
            if (!__all(tm <= m_run[qf])) {                                     \
                const float nm = fmaxf(m_run[qf], tm);                         \
                const float corr = exp2f(m_run[qf] - nm);                      \
                m_run[qf] = nm;                                                \
                l_part[qf] *= corr;                                            \
                _Pragma("unroll")                                              \
                for (int f = 0; f < 4; ++f)                                    \
                    _Pragma("unroll")                                          \
                    for (int r = 0; r < 4; ++r) of[f][qf][r] *= corr;          \
            }                                                                  \
            _Pragma("unroll")                                                  \
            for (int f = 0; f < 4; ++f)                                        \
                _Pragma("unroll")                                              \
                for (int r = 0; r < 4; ++r) {                                  \
                    sf[f][qf][r] = exp2f(sf[f][qf][r] - m_run[qf]);            \
                    l_part[qf] += sf[f][qf][r];                                \
                }                                                              \
            _Pragma("unroll")                                                  \
            for (int c = 0; c < 2; ++c) {                                      \
                const unsigned A0 = cvt_pk_bf16(sf[2*c][qf][0], sf[2*c][qf][1]);   \
                const unsigned A1 = cvt_pk_bf16(sf[2*c][qf][2], sf[2*c][qf][3]);   \
                const unsigned B0 = cvt_pk_bf16(sf[2*c+1][qf][0], sf[2*c+1][qf][1]); \
                const unsigned B1 = cvt_pk_bf16(sf[2*c+1][qf][2], sf[2*c+1][qf][3]); \
                const unsigned s0 = lgp ? A0 : B0;                             \
                const unsigned s1 = lgp ? A1 : B1;                             \
                const unsigned r0 = (unsigned)__shfl_xor((int)s0, 16);         \
                const unsigned r1 = (unsigned)__shfl_xor((int)s1, 16);         \
                const unsigned o0 = lgp ? B0 : A0;                             \
                const unsigned o1 = lgp ? B1 : A1;                             \
                u32x4 wvv;                                                     \
                wvv[0] = lgp ? r0 : o0;                                        \
                wvv[1] = lgp ? r1 : o1;                                        \
                wvv[2] = lgp ? o0 : r0;                                        \
                wvv[3] = lgp ? o1 : r1;                                        \
                pb[qf][c] = __builtin_bit_cast(bf16x8, wvv);                   \
            }                                                                  \
        }                                                                      \
        __builtin_amdgcn_s_setprio(1);                                         \
        _Pragma("unroll")                                                      \
        for (int fA = 0; fA < 4; ++fA)                                         \
            _Pragma("unroll")                                                  \
            for (int c = 0; c < 2; ++c)                                        \
                _Pragma("unroll")                                              \
                for (int qf = 0; qf < 2; ++qf)                                 \
                    of[fA][qf] = __builtin_amdgcn_mfma_f32_16x16x32_bf16(      \
                        vv[fA][c], pb[qf][c], of[fA][qf], 0, 0, 0);            \
        __builtin_amdgcn_s_setprio(0);                                         \
    }

    bf16x8 kA[4][2], kB_[4][2];
    LOADK(kA, 0);
    int kt = 0;
    while (true) {
        TILE_BODY(kA, kB_, kt);
        if (++kt == ntiles) break;
        TILE_BODY(kB_, kA, kt);
        if (++kt == ntiles) break;
    }
#undef TILE_BODY
#undef LOADK

    // ---- epilogue ----
    const int bb = bh / NH, hh = bh - bb * NH;
#pragma unroll
    for (int qf = 0; qf < 2; ++qf) {
        float l = l_part[qf];
        l += __shfl_xor(l, 16);
        l += __shfl_xor(l, 32);
        const float inv = 1.f / l;
        unsigned short* op = AO + ((size_t)(bb * NS + q0 + qf * 16 + lr)) * ND + hh * NHD;
#pragma unroll
        for (int fA = 0; fA < 4; ++fA) {
            ushort4 o4;
            o4.x = f2bf(of[fA][qf][0] * inv);
            o4.y = f2bf(of[fA][qf][1] * inv);
            o4.z = f2bf(of[fA][qf][2] * inv);
            o4.w = f2bf(of[fA][qf][3] * inv);
            *reinterpret_cast<ushort4*>(op + fA * 16 + lg * 4) = o4;
        }
    }
}

// ---------------------------------------------------------------------------
extern "C" void kernel_launch(void* const* d_in, const int* in_sizes, int n_in,
                              void* d_out, int out_size, void* d_ws, size_t ws_size,
                              hipStream_t stream) {
    const float* hs   = (const float*)d_in[0];
    const float* Wqkv = (const float*)d_in[1];
    const float* bqkv = (const float*)d_in[2];
    const float* Wout = (const float*)d_in[3];
    const float* bout = (const float*)d_in[4];
    float* out = (float*)d_out;

    char* wp = (char*)d_ws;
    unsigned short* hsb = (unsigned short*)wp; wp += (size_t)NM * ND * 2;
    unsigned short* W1t = (unsigned short*)wp; wp += (size_t)N3D * ND * 2;
    unsigned short* W2t = (unsigned short*)wp; wp += (size_t)ND * ND * 2;
    const size_t per = (size_t)NB * NH * NS * NHD;
    unsigned short* Qb  = (unsigned short*)wp; wp += per * 2;
    unsigned short* Kb  = (unsigned short*)wp; wp += per * 2;
    unsigned short* Vtb = (unsigned short*)wp; wp += per * 2;
    unsigned short* AOb = (unsigned short*)wp; wp += per * 2;
    // AOb doubles as the temporary coalesced-V buffer: qkv writes V there,
    // vtransp consumes it into Vtb, then attn overwrites AOb with its output.

    prep<<<3072 + 1728 + 576, 256, 0, stream>>>(hs, hsb, Wqkv, W1t, Wout, W2t);

    gemm_k768<128, 128, 0><<<dim3(N3D / 128, NM / 128), 256, 0, stream>>>(
        hsb, W1t, bqkv, Qb, Kb, AOb, nullptr);

    vtransp<<<dim3(NS / 64, NB * NH), 256, 0, stream>>>(AOb, Vtb);

    attn_mfma<<<NS / 32 * NB * NH, 64, 0, stream>>>(Qb, Kb, Vtb, AOb);

    gemm_k768<64, 64, 1><<<dim3(ND / 64, NM / 64), 256, 0, stream>>>(
        AOb, W2t, bout, nullptr, nullptr, nullptr, out);
}

// Round 8
// 165.706 us; speedup vs baseline: 1.2274x; 1.2274x over previous
//
#include <hip/hip_runtime.h>
#include <hip/hip_bf16.h>

typedef __attribute__((ext_vector_type(8))) short bf16x8;
typedef __attribute__((ext_vector_type(4))) float f32x4;
typedef __attribute__((ext_vector_type(4))) unsigned int u32x4;

#define NB 2
#define NS 2048
#define ND 768
#define NH 12
#define NHD 64
#define N3D 2304
#define NM (NB * NS)   // 4096 rows

__device__ __forceinline__ unsigned short f2bf(float x) {
    union { float f; unsigned u; } v; v.f = x;
    unsigned r = v.u + 0x7FFFu + ((v.u >> 16) & 1u);   // RNE
    return (unsigned short)(r >> 16);
}

__device__ __forceinline__ unsigned cvt_pk_bf16(float lo, float hi) {
    unsigned r;
    asm volatile("v_cvt_pk_bf16_f32 %0, %1, %2" : "=v"(r) : "v"(lo), "v"(hi));
    return r;   // D.bf16[0] = lo, D.bf16[1] = hi
}

// ---------------------------------------------------------------------------
// Fused prep: region A = hs f32->bf16 convert (3072 blocks);
// region B = Wqkv transpose+convert (1728 blocks);
// region C = Wout transpose+convert (576 blocks).
// ---------------------------------------------------------------------------
__device__ __forceinline__ void transp_tile(const float* __restrict__ in,
                                            unsigned short* __restrict__ out,
                                            int K, int N, int nt, int kt,
                                            float (*T)[33]) {
    const int n0 = nt * 32, k0 = kt * 32;
    const int r = threadIdx.x >> 3, c4 = (threadIdx.x & 7) * 4;
    float4 v = *reinterpret_cast<const float4*>(&in[(size_t)(k0 + r) * N + n0 + c4]);
    T[r][c4 + 0] = v.x; T[r][c4 + 1] = v.y; T[r][c4 + 2] = v.z; T[r][c4 + 3] = v.w;
    __syncthreads();
    ushort4 o;
    o.x = f2bf(T[c4 + 0][r]); o.y = f2bf(T[c4 + 1][r]);
    o.z = f2bf(T[c4 + 2][r]); o.w = f2bf(T[c4 + 3][r]);
    *reinterpret_cast<ushort4*>(&out[(size_t)(n0 + r) * K + k0 + c4]) = o;
}

__global__ __launch_bounds__(256)
void prep(const float* __restrict__ hs, unsigned short* __restrict__ hsb,
          const float* __restrict__ Wqkv, unsigned short* __restrict__ W1t,
          const float* __restrict__ Wout, unsigned short* __restrict__ W2t) {
    __shared__ float T[32][33];
    const int bid = blockIdx.x;
    if (bid < 3072) {
        const int i = (bid * 256 + threadIdx.x) * 4;
        float4 v = *reinterpret_cast<const float4*>(hs + i);
        ushort4 o;
        o.x = f2bf(v.x); o.y = f2bf(v.y); o.z = f2bf(v.z); o.w = f2bf(v.w);
        *reinterpret_cast<ushort4*>(hsb + i) = o;
    } else if (bid < 3072 + 1728) {
        const int idx = bid - 3072;                 // Wqkv: 72 n-tiles x 24 k-tiles
        transp_tile(Wqkv, W1t, ND, N3D, idx % 72, idx / 72, T);
    } else {
        const int idx = bid - 4800;                 // Wout: 24 x 24
        transp_tile(Wout, W2t, ND, ND, idx % 24, idx / 24, T);
    }
}

// ---------------------------------------------------------------------------
// bf16 MFMA GEMM, K=768, m97-style single-buffer.
// EPI=0 (BM=128, BN=96 -> 768 blocks = exactly 3/CU): QKV epilogue.
//   sec 0/1: Q(*0.125*log2e)/K coalesced [B,H,S,HD].
//   sec 2:   V transposed IN-KERNEL via swizzled LDS reuse -> Vt [B,H,HD,S]
//            (replaces the separate vtransp kernel; coalesced 256B runs).
// EPI=1: plain epilogue -> Co f32 [M][768] + bias.
// ---------------------------------------------------------------------------
template<int BM, int BN, int EPI>
__global__ __launch_bounds__(256)
void gemm_k768(const unsigned short* __restrict__ A,
               const unsigned short* __restrict__ Bt,
               const float* __restrict__ bias,
               unsigned short* __restrict__ Qo, unsigned short* __restrict__ Ko,
               unsigned short* __restrict__ Vto, float* __restrict__ Co) {
    __shared__ unsigned short SMEM[(BM + BN) * 64];
    unsigned short* As = SMEM;
    unsigned short* Bs = SMEM + BM * 64;
    const int t = threadIdx.x;
    const int wv = t >> 6, lane = t & 63;
    const int lr = lane & 15, lg = lane >> 4;
    const int wr = wv >> 1, wc = wv & 1;
    const int m0 = blockIdx.y * BM;
    const int n0 = blockIdx.x * BN;
    constexpr int FM = BM / 32;
    constexpr int FN = BN / 32;

    f32x4 acc[FM][FN];
#pragma unroll
    for (int i = 0; i < FM; ++i)
#pragma unroll
        for (int j = 0; j < FN; ++j) acc[i][j] = (f32x4){0.f, 0.f, 0.f, 0.f};

    const int sr = t >> 3;
    const int sb = t & 7;

    for (int ki = 0; ki < ND / 64; ++ki) {
        const int k0 = ki * 64;
        __syncthreads();                    // prev compute's LDS reads done
#pragma unroll
        for (int jj = 0; jj < BM / 32; ++jj) {
            const int row = jj * 32 + sr;
            __builtin_amdgcn_global_load_lds(
                (const void*)(A + (size_t)(m0 + row) * ND + k0 + ((sb ^ (row & 7)) * 8)),
                (void*)(As + jj * 2048 + wv * 512), 16, 0, 0);
        }
#pragma unroll
        for (int jj = 0; jj < BN / 32; ++jj) {
            const int row = jj * 32 + sr;
            __builtin_amdgcn_global_load_lds(
                (const void*)(Bt + (size_t)(n0 + row) * ND + k0 + ((sb ^ (row & 7)) * 8)),
                (void*)(Bs + jj * 2048 + wv * 512), 16, 0, 0);
        }
        __syncthreads();                    // staged tile visible
#pragma unroll
        for (int kc = 0; kc < 2; ++kc) {
            bf16x8 af[FM], bfr[FN];
#pragma unroll
            for (int mi = 0; mi < FM; ++mi) {
                const int row = wr * (BM / 2) + mi * 16 + lr;
                af[mi] = *(const bf16x8*)&As[row * 64 + (((kc * 4 + lg) ^ (row & 7)) * 8)];
            }
#pragma unroll
            for (int nj = 0; nj < FN; ++nj) {
                const int row = wc * (BN / 2) + nj * 16 + lr;
                bfr[nj] = *(const bf16x8*)&Bs[row * 64 + (((kc * 4 + lg) ^ (row & 7)) * 8)];
            }
#pragma unroll
            for (int mi = 0; mi < FM; ++mi)
#pragma unroll
                for (int nj = 0; nj < FN; ++nj)
                    acc[mi][nj] = __builtin_amdgcn_mfma_f32_16x16x32_bf16(
                        af[mi], bfr[nj], acc[mi][nj], 0, 0, 0);
        }
    }

    if (EPI == 0) {
        const int sec = n0 / ND;            // block-uniform (768 % BN-section ok)
        if (sec < 2) {
#pragma unroll
            for (int mi = 0; mi < FM; ++mi) {
#pragma unroll
                for (int nj = 0; nj < FN; ++nj) {
                    const int n = n0 + wc * (BN / 2) + nj * 16 + lr;
                    const int rem = n - sec * ND;
                    const int hh = rem >> 6, dd = rem & 63;
                    const float b = bias[n];
#pragma unroll
                    for (int r = 0; r < 4; ++r) {
                        const int m = m0 + wr * (BM / 2) + mi * 16 + lg * 4 + r;
                        const int bb = m >> 11, ss = m & (NS - 1);
                        const int bhh = bb * NH + hh;
                        const float v = acc[mi][nj][r] + b;
                        if (sec == 0)   // 0.125 * log2(e): attention uses exp2
                            Qo[((size_t)bhh * NS + ss) * NHD + dd] = f2bf(v * 0.18033688011112042f);
                        else
                            Ko[((size_t)bhh * NS + ss) * NHD + dd] = f2bf(v);
                    }
                }
            }
        } else {
            // ---- V section: transpose via swizzled LDS reuse -> Vt ----
            // (assumes BM=128: T is [BN][128] bf16, row = 256 B)
            __syncthreads();                // all MFMA LDS reads done
            char* Tb = reinterpret_cast<char*>(SMEM);
#pragma unroll
            for (int mi = 0; mi < FM; ++mi) {
#pragma unroll
                for (int nj = 0; nj < FN; ++nj) {
                    const int n_l = wc * (BN / 2) + nj * 16 + lr;
                    const int m_l = wr * (BM / 2) + mi * 16 + lg * 4;
                    const float b = bias[n0 + n_l];
                    ushort4 pk;
                    pk.x = f2bf(acc[mi][nj][0] + b);
                    pk.y = f2bf(acc[mi][nj][1] + b);
                    pk.z = f2bf(acc[mi][nj][2] + b);
                    pk.w = f2bf(acc[mi][nj][3] + b);
                    const int off = n_l * 256 + (((m_l * 2) ^ ((n_l & 15) << 4)));
                    *reinterpret_cast<ushort4*>(Tb + off) = pk;   // 8B, 2-way free
                }
            }
            __syncthreads();
            const int bb = m0 >> 11;        // block-uniform (BM=128 | 2048)
            const int ssb = m0 & (NS - 1);
#pragma unroll
            for (int h = 0; h < (BN * 16) / 256; ++h) {   // BN*128 elems / 8 per rd
                const int p = t + 256 * h;
                const int n_l = p >> 4, j = p & 15;
                const int off = n_l * 256 + (((j ^ (n_l & 15)) << 4));
                bf16x8 v = *reinterpret_cast<const bf16x8*>(Tb + off);  // m=8j..8j+7
                const int rem = n0 + n_l - 2 * ND;
                const int hh = rem >> 6, dd = rem & 63;
                const int bhh = bb * NH + hh;
                *reinterpret_cast<bf16x8*>(Vto + ((size_t)(bhh * NHD + dd)) * NS + ssb + 8 * j) = v;
            }
        }
    } else {
#pragma unroll
        for (int mi = 0; mi < FM; ++mi)
#pragma unroll
            for (int nj = 0; nj < FN; ++nj) {
                const int n = n0 + wc * (BN / 2) + nj * 16 + lr;
                const float b = bias[n];
#pragma unroll
                for (int r = 0; r < 4; ++r) {
                    const int m = m0 + wr * (BM / 2) + mi * 16 + lg * 4 + r;
                    Co[(size_t)m * ND + n] = acc[mi][nj][r] + b;
                }
            }
    }
}

// ---------------------------------------------------------------------------
// Causal flash attention, swapped-QK^T bf16 MFMA, KVBLK=64 double-buffered.
// (round-6 version verbatim: best measured 58.4 us; round-7 wave-private
// variant regressed — TLP loss dominated.)
// ---------------------------------------------------------------------------
__global__ __launch_bounds__(256)
void attn_mfma(const unsigned short* __restrict__ Qg,
               const unsigned short* __restrict__ Kg,
               const unsigned short* __restrict__ Vtg,
               unsigned short* __restrict__ AO) {
    __shared__ unsigned short Ks[2][64 * 64];
    __shared__ unsigned short Vs[2][64 * 64];
    const int n = blockIdx.x;               // 768 blocks
    const int x = n & 7, ii = n >> 3;       // XCD = n%8; 96 blocks per XCD
    const int bh = ((ii >> 5) << 3) + x;    // 3 bh per XCD
    const int qt = (31 - (ii & 31) + 11 * (ii >> 5)) & 31;
    const int t = threadIdx.x;
    const int w = t >> 6, lane = t & 63;
    const int lr = lane & 15, lg = lane >> 4;
    const int lgp = lg & 1;
    const int qrow = qt * 64 + w * 16 + lr;
    const size_t bhoff = (size_t)bh * (NS * NHD);

    // Q as MFMA B-operand: lane supplies Q[q=lr][d = 32c + lg*8 + i]
    const unsigned short* Qp = Qg + bhoff + (size_t)qrow * NHD;
    const bf16x8 qB0 = *(const bf16x8*)(Qp + lg * 8);
    const bf16x8 qB1 = *(const bf16x8*)(Qp + 32 + lg * 8);

    float m_run = -1e30f, l_part = 0.f;
    f32x4 of[4];
#pragma unroll
    for (int f = 0; f < 4; ++f) of[f] = (f32x4){0.f, 0.f, 0.f, 0.f};

    const unsigned short* Kb = Kg + bhoff;
    const unsigned short* Vb = Vtg + bhoff;
    const int srow = lane >> 3, sblk = lane & 7;
    const int ntiles = qt + 1;
    const int bswz = ((lg & 1) << 1) | (lg >> 1);     // kv-block sigma

#define STAGE(buf, kv0)                                                           \
    {                                                                             \
        _Pragma("unroll")                                                         \
        for (int h = 0; h < 2; ++h) {                                             \
            const int rr = w * 16 + h * 8 + srow;                                 \
            __builtin_amdgcn_global_load_lds(                                     \
                (const void*)(Kb + (size_t)((kv0) + rr) * NHD + ((sblk ^ (rr & 7)) * 8)),  \
                (void*)(Ks[buf] + (w * 16 + h * 8) * 64), 16, 0, 0);              \
            __builtin_amdgcn_global_load_lds(                                     \
                (const void*)(Vb + (size_t)rr * NS + (kv0) + ((sblk ^ (rr & 7)) * 8)),     \
                (void*)(Vs[buf] + (w * 16 + h * 8) * 64), 16, 0, 0);              \
        }                                                                         \
    }

    STAGE(0, 0);
    for (int kt = 0; kt < ntiles; ++kt) {
        __syncthreads();               // tile kt visible; prev-tile reads done
        if (kt + 1 < ntiles) STAGE((kt + 1) & 1, (kt + 1) * 64);
        const unsigned short* Kc = Ks[kt & 1];
        const unsigned short* Vc = Vs[kt & 1];
        const int kv0 = kt * 64;

        // ---- S^T = K Q^T : 4 kv-frags x 2 d-chunks ----
        f32x4 sf[4];
#pragma unroll
        for (int f = 0; f < 4; ++f) sf[f] = (f32x4){0.f, 0.f, 0.f, 0.f};
        __builtin_amdgcn_s_setprio(1);
#pragma unroll
        for (int f = 0; f < 4; ++f) {
            const int krow = f * 16 + lr;
            const bf16x8 a0 = *(const bf16x8*)&Kc[krow * 64 + ((lg ^ (krow & 7)) * 8)];
            const bf16x8 a1 = *(const bf16x8*)&Kc[krow * 64 + (((4 + lg) ^ (krow & 7)) * 8)];
            sf[f] = __builtin_amdgcn_mfma_f32_16x16x32_bf16(a0, qB0, sf[f], 0, 0, 0);
            sf[f] = __builtin_amdgcn_mfma_f32_16x16x32_bf16(a1, qB1, sf[f], 0, 0, 0);
        }
        __builtin_amdgcn_s_setprio(0);

        if (kt == ntiles - 1) {        // causal mask, last tile only
            const int thr = qrow - kv0;
#pragma unroll
            for (int f = 0; f < 4; ++f)
#pragma unroll
                for (int r = 0; r < 4; ++r)
                    if (f * 16 + lg * 4 + r > thr) sf[f][r] = -1e30f;
        }

        // ---- online softmax (exp2 domain), deferred-l ----
        float tm = -1e30f;
#pragma unroll
        for (int f = 0; f < 4; ++f)
            tm = fmaxf(tm, fmaxf(fmaxf(sf[f][0], sf[f][1]), fmaxf(sf[f][2], sf[f][3])));
        tm = fmaxf(tm, __shfl_xor(tm, 16));
        tm = fmaxf(tm, __shfl_xor(tm, 32));
        if (!__all(tm <= m_run)) {
            const float nm = fmaxf(m_run, tm);
            const float corr = exp2f(m_run - nm);
            m_run = nm;
            l_part *= corr;
#pragma unroll
            for (int f = 0; f < 4; ++f)
#pragma unroll
                for (int r = 0; r < 4; ++r) of[f][r] *= corr;
        }
#pragma unroll
        for (int f = 0; f < 4; ++f)
#pragma unroll
            for (int r = 0; r < 4; ++r) {
                sf[f][r] = exp2f(sf[f][r] - m_run);
                l_part += sf[f][r];
            }

        // ---- pack P^T (sigma kv-permutation, partner exchange over xor16) ----
        bf16x8 pb[2];
#pragma unroll
        for (int c = 0; c < 2; ++c) {
            const unsigned A0 = cvt_pk_bf16(sf[2 * c][0], sf[2 * c][1]);
            const unsigned A1 = cvt_pk_bf16(sf[2 * c][2], sf[2 * c][3]);
            const unsigned B0 = cvt_pk_bf16(sf[2 * c + 1][0], sf[2 * c + 1][1]);
            const unsigned B1 = cvt_pk_bf16(sf[2 * c + 1][2], sf[2 * c + 1][3]);
            const unsigned s0 = lgp ? A0 : B0;
            const unsigned s1 = lgp ? A1 : B1;
            const unsigned r0 = (unsigned)__shfl_xor((int)s0, 16);
            const unsigned r1 = (unsigned)__shfl_xor((int)s1, 16);
            const unsigned o0 = lgp ? B0 : A0;
            const unsigned o1 = lgp ? B1 : A1;
            u32x4 wvv;
            wvv[0] = lgp ? r0 : o0;
            wvv[1] = lgp ? r1 : o1;
            wvv[2] = lgp ? o0 : r0;
            wvv[3] = lgp ? o1 : r1;
            pb[c] = __builtin_bit_cast(bf16x8, wvv);
        }

        // ---- O^T += Vt P^T ----
        __builtin_amdgcn_s_setprio(1);
#pragma unroll
        for (int fA = 0; fA < 4; ++fA) {
            const int drow = fA * 16 + lr;
#pragma unroll
            for (int c = 0; c < 2; ++c) {
                const int blk = 4 * c + bswz;
                const bf16x8 va = *(const bf16x8*)&Vc[drow * 64 + ((blk ^ (drow & 7)) * 8)];
                of[fA] = __builtin_amdgcn_mfma_f32_16x16x32_bf16(va, pb[c], of[fA], 0, 0, 0);
            }
        }
        __builtin_amdgcn_s_setprio(0);
    }
#undef STAGE

    // ---- final l reduce + epilogue (O^T rows contiguous in d) ----
    l_part += __shfl_xor(l_part, 16);
    l_part += __shfl_xor(l_part, 32);
    const float inv = 1.f / l_part;
    const int bb = bh / NH, hh = bh - bb * NH;
    unsigned short* op = AO + ((size_t)(bb * NS + qrow)) * ND + hh * NHD;
#pragma unroll
    for (int fA = 0; fA < 4; ++fA) {
        ushort4 o4;
        o4.x = f2bf(of[fA][0] * inv);
        o4.y = f2bf(of[fA][1] * inv);
        o4.z = f2bf(of[fA][2] * inv);
        o4.w = f2bf(of[fA][3] * inv);
        *reinterpret_cast<ushort4*>(op + fA * 16 + lg * 4) = o4;
    }
}

// ---------------------------------------------------------------------------
extern "C" void kernel_launch(void* const* d_in, const int* in_sizes, int n_in,
                              void* d_out, int out_size, void* d_ws, size_t ws_size,
                              hipStream_t stream) {
    const float* hs   = (const float*)d_in[0];
    const float* Wqkv = (const float*)d_in[1];
    const float* bqkv = (const float*)d_in[2];
    const float* Wout = (const float*)d_in[3];
    const float* bout = (const float*)d_in[4];
    float* out = (float*)d_out;

    char* wp = (char*)d_ws;
    unsigned short* hsb = (unsigned short*)wp; wp += (size_t)NM * ND * 2;
    unsigned short* W1t = (unsigned short*)wp; wp += (size_t)N3D * ND * 2;
    unsigned short* W2t = (unsigned short*)wp; wp += (size_t)ND * ND * 2;
    const size_t per = (size_t)NB * NH * NS * NHD;
    unsigned short* Qb  = (unsigned short*)wp; wp += per * 2;
    unsigned short* Kb  = (unsigned short*)wp; wp += per * 2;
    unsigned short* Vtb = (unsigned short*)wp; wp += per * 2;
    unsigned short* AOb = (unsigned short*)wp; wp += per * 2;

    prep<<<3072 + 1728 + 576, 256, 0, stream>>>(hs, hsb, Wqkv, W1t, Wout, W2t);

    // BN=96 -> 24x32 = 768 blocks = exactly 3/CU; Vt written in-epilogue
    gemm_k768<128, 96, 0><<<dim3(N3D / 96, NM / 128), 256, 0, stream>>>(
        hsb, W1t, bqkv, Qb, Kb, Vtb, nullptr);

    attn_mfma<<<dim3(NS / 64 * NB * NH), 256, 0, stream>>>(Qb, Kb, Vtb, AOb);

    gemm_k768<64, 64, 1><<<dim3(ND / 64, NM / 64), 256, 0, stream>>>(
        AOb, W2t, bout, nullptr, nullptr, nullptr, out);
}

// Round 9
// 155.254 us; speedup vs baseline: 1.3100x; 1.0673x over previous
//
#include <hip/hip_runtime.h>
#include <hip/hip_bf16.h>

typedef __attribute__((ext_vector_type(8))) short bf16x8;
typedef __attribute__((ext_vector_type(4))) float f32x4;
typedef __attribute__((ext_vector_type(4))) unsigned int u32x4;

#define NB 2
#define NS 2048
#define ND 768
#define NH 12
#define NHD 64
#define N3D 2304
#define NM (NB * NS)   // 4096 rows

__device__ __forceinline__ unsigned short f2bf(float x) {
    union { float f; unsigned u; } v; v.f = x;
    unsigned r = v.u + 0x7FFFu + ((v.u >> 16) & 1u);   // RNE
    return (unsigned short)(r >> 16);
}

__device__ __forceinline__ unsigned cvt_pk_bf16(float lo, float hi) {
    unsigned r;
    asm volatile("v_cvt_pk_bf16_f32 %0, %1, %2" : "=v"(r) : "v"(lo), "v"(hi));
    return r;   // D.bf16[0] = lo, D.bf16[1] = hi
}

__device__ __forceinline__ float fexp2(float x) {   // raw v_exp_f32 (2^x)
    float r;
    asm("v_exp_f32 %0, %1" : "=v"(r) : "v"(x));
    return r;
}

// ---------------------------------------------------------------------------
// Fused prep: region A = hs f32->bf16 convert (3072 blocks);
// region B = Wqkv transpose+convert (1728 blocks);
// region C = Wout transpose+convert (576 blocks).
// ---------------------------------------------------------------------------
__device__ __forceinline__ void transp_tile(const float* __restrict__ in,
                                            unsigned short* __restrict__ out,
                                            int K, int N, int nt, int kt,
                                            float (*T)[33]) {
    const int n0 = nt * 32, k0 = kt * 32;
    const int r = threadIdx.x >> 3, c4 = (threadIdx.x & 7) * 4;
    float4 v = *reinterpret_cast<const float4*>(&in[(size_t)(k0 + r) * N + n0 + c4]);
    T[r][c4 + 0] = v.x; T[r][c4 + 1] = v.y; T[r][c4 + 2] = v.z; T[r][c4 + 3] = v.w;
    __syncthreads();
    ushort4 o;
    o.x = f2bf(T[c4 + 0][r]); o.y = f2bf(T[c4 + 1][r]);
    o.z = f2bf(T[c4 + 2][r]); o.w = f2bf(T[c4 + 3][r]);
    *reinterpret_cast<ushort4*>(&out[(size_t)(n0 + r) * K + k0 + c4]) = o;
}

__global__ __launch_bounds__(256)
void prep(const float* __restrict__ hs, unsigned short* __restrict__ hsb,
          const float* __restrict__ Wqkv, unsigned short* __restrict__ W1t,
          const float* __restrict__ Wout, unsigned short* __restrict__ W2t) {
    __shared__ float T[32][33];
    const int bid = blockIdx.x;
    if (bid < 3072) {
        const int i = (bid * 256 + threadIdx.x) * 4;
        float4 v = *reinterpret_cast<const float4*>(hs + i);
        ushort4 o;
        o.x = f2bf(v.x); o.y = f2bf(v.y); o.z = f2bf(v.z); o.w = f2bf(v.w);
        *reinterpret_cast<ushort4*>(hsb + i) = o;
    } else if (bid < 3072 + 1728) {
        const int idx = bid - 3072;                 // Wqkv: 72 n-tiles x 24 k-tiles
        transp_tile(Wqkv, W1t, ND, N3D, idx % 72, idx / 72, T);
    } else {
        const int idx = bid - 4800;                 // Wout: 24 x 24
        transp_tile(Wout, W2t, ND, ND, idx % 24, idx / 24, T);
    }
}

// ---------------------------------------------------------------------------
// bf16 MFMA GEMM, K=768, m97-style single-buffer.
// EPI=0 (BM=128, BN=96 -> 768 blocks = exactly 3/CU): QKV epilogue.
//   sec 0/1: Q(*0.125*log2e)/K coalesced [B,H,S,HD].
//   sec 2:   V transposed IN-KERNEL via swizzled LDS reuse -> Vt [B,H,HD,S].
// EPI=1: plain epilogue -> Co f32 [M][768] + bias.
// ---------------------------------------------------------------------------
template<int BM, int BN, int EPI>
__global__ __launch_bounds__(256)
void gemm_k768(const unsigned short* __restrict__ A,
               const unsigned short* __restrict__ Bt,
               const float* __restrict__ bias,
               unsigned short* __restrict__ Qo, unsigned short* __restrict__ Ko,
               unsigned short* __restrict__ Vto, float* __restrict__ Co) {
    __shared__ unsigned short SMEM[(BM + BN) * 64];
    unsigned short* As = SMEM;
    unsigned short* Bs = SMEM + BM * 64;
    const int t = threadIdx.x;
    const int wv = t >> 6, lane = t & 63;
    const int lr = lane & 15, lg = lane >> 4;
    const int wr = wv >> 1, wc = wv & 1;
    const int m0 = blockIdx.y * BM;
    const int n0 = blockIdx.x * BN;
    constexpr int FM = BM / 32;
    constexpr int FN = BN / 32;

    f32x4 acc[FM][FN];
#pragma unroll
    for (int i = 0; i < FM; ++i)
#pragma unroll
        for (int j = 0; j < FN; ++j) acc[i][j] = (f32x4){0.f, 0.f, 0.f, 0.f};

    const int sr = t >> 3;
    const int sb = t & 7;

    for (int ki = 0; ki < ND / 64; ++ki) {
        const int k0 = ki * 64;
        __syncthreads();                    // prev compute's LDS reads done
#pragma unroll
        for (int jj = 0; jj < BM / 32; ++jj) {
            const int row = jj * 32 + sr;
            __builtin_amdgcn_global_load_lds(
                (const void*)(A + (size_t)(m0 + row) * ND + k0 + ((sb ^ (row & 7)) * 8)),
                (void*)(As + jj * 2048 + wv * 512), 16, 0, 0);
        }
#pragma unroll
        for (int jj = 0; jj < BN / 32; ++jj) {
            const int row = jj * 32 + sr;
            __builtin_amdgcn_global_load_lds(
                (const void*)(Bt + (size_t)(n0 + row) * ND + k0 + ((sb ^ (row & 7)) * 8)),
                (void*)(Bs + jj * 2048 + wv * 512), 16, 0, 0);
        }
        __syncthreads();                    // staged tile visible
#pragma unroll
        for (int kc = 0; kc < 2; ++kc) {
            bf16x8 af[FM], bfr[FN];
#pragma unroll
            for (int mi = 0; mi < FM; ++mi) {
                const int row = wr * (BM / 2) + mi * 16 + lr;
                af[mi] = *(const bf16x8*)&As[row * 64 + (((kc * 4 + lg) ^ (row & 7)) * 8)];
            }
#pragma unroll
            for (int nj = 0; nj < FN; ++nj) {
                const int row = wc * (BN / 2) + nj * 16 + lr;
                bfr[nj] = *(const bf16x8*)&Bs[row * 64 + (((kc * 4 + lg) ^ (row & 7)) * 8)];
            }
#pragma unroll
            for (int mi = 0; mi < FM; ++mi)
#pragma unroll
                for (int nj = 0; nj < FN; ++nj)
                    acc[mi][nj] = __builtin_amdgcn_mfma_f32_16x16x32_bf16(
                        af[mi], bfr[nj], acc[mi][nj], 0, 0, 0);
        }
    }

    if (EPI == 0) {
        const int sec = n0 / ND;            // block-uniform
        if (sec < 2) {
#pragma unroll
            for (int mi = 0; mi < FM; ++mi) {
#pragma unroll
                for (int nj = 0; nj < FN; ++nj) {
                    const int n = n0 + wc * (BN / 2) + nj * 16 + lr;
                    const int rem = n - sec * ND;
                    const int hh = rem >> 6, dd = rem & 63;
                    const float b = bias[n];
#pragma unroll
                    for (int r = 0; r < 4; ++r) {
                        const int m = m0 + wr * (BM / 2) + mi * 16 + lg * 4 + r;
                        const int bb = m >> 11, ss = m & (NS - 1);
                        const int bhh = bb * NH + hh;
                        const float v = acc[mi][nj][r] + b;
                        if (sec == 0)   // 0.125 * log2(e): attention uses exp2
                            Qo[((size_t)bhh * NS + ss) * NHD + dd] = f2bf(v * 0.18033688011112042f);
                        else
                            Ko[((size_t)bhh * NS + ss) * NHD + dd] = f2bf(v);
                    }
                }
            }
        } else {
            // ---- V section: transpose via swizzled LDS reuse -> Vt ----
            __syncthreads();                // all MFMA LDS reads done
            char* Tb = reinterpret_cast<char*>(SMEM);
#pragma unroll
            for (int mi = 0; mi < FM; ++mi) {
#pragma unroll
                for (int nj = 0; nj < FN; ++nj) {
                    const int n_l = wc * (BN / 2) + nj * 16 + lr;
                    const int m_l = wr * (BM / 2) + mi * 16 + lg * 4;
                    const float b = bias[n0 + n_l];
                    ushort4 pk;
                    pk.x = f2bf(acc[mi][nj][0] + b);
                    pk.y = f2bf(acc[mi][nj][1] + b);
                    pk.z = f2bf(acc[mi][nj][2] + b);
                    pk.w = f2bf(acc[mi][nj][3] + b);
                    const int off = n_l * 256 + (((m_l * 2) ^ ((n_l & 15) << 4)));
                    *reinterpret_cast<ushort4*>(Tb + off) = pk;   // 8B, 2-way free
                }
            }
            __syncthreads();
            const int bb = m0 >> 11;
            const int ssb = m0 & (NS - 1);
#pragma unroll
            for (int h = 0; h < (BN * 16) / 256; ++h) {
                const int pp = t + 256 * h;
                const int n_l = pp >> 4, j = pp & 15;
                const int off = n_l * 256 + (((j ^ (n_l & 15)) << 4));
                bf16x8 v = *reinterpret_cast<const bf16x8*>(Tb + off);
                const int rem = n0 + n_l - 2 * ND;
                const int hh = rem >> 6, dd = rem & 63;
                const int bhh = bb * NH + hh;
                *reinterpret_cast<bf16x8*>(Vto + ((size_t)(bhh * NHD + dd)) * NS + ssb + 8 * j) = v;
            }
        }
    } else {
#pragma unroll
        for (int mi = 0; mi < FM; ++mi)
#pragma unroll
            for (int nj = 0; nj < FN; ++nj) {
                const int n = n0 + wc * (BN / 2) + nj * 16 + lr;
                const float b = bias[n];
#pragma unroll
                for (int r = 0; r < 4; ++r) {
                    const int m = m0 + wr * (BM / 2) + mi * 16 + lg * 4 + r;
                    Co[(size_t)m * ND + n] = acc[mi][nj][r] + b;
                }
            }
    }
}

// ---------------------------------------------------------------------------
// Causal flash attention v4: perfectly CU-balanced.
//   Block = 32 q-rows; waves {0,1} kv[0..63], waves {2,3} kv[64..127] of a
//   KVBLK-128 round (kv-split; cross-half merge via LDS once per member).
//   Each block runs TWO members sequentially: q-tiles {63-j, j} -> rounds
//   per block = (63-j)/4 + j/4 + 2 = 17 for EVERY j. 768 blocks = 3/CU,
//   identical length (old map had per-CU sums 35..65).
//   K double-buffered + V single (48 KB); V(R)+K(R+1) issued at round start,
//   drained at mid-round barrier -> latency hidden under QK^T/softmax.
//   exp2 via raw v_exp_f32 (libm exp2f carries range-check VALU bloat).
// ---------------------------------------------------------------------------
__global__ __launch_bounds__(256)
void attn_mfma(const unsigned short* __restrict__ Qg,
               const unsigned short* __restrict__ Kg,
               const unsigned short* __restrict__ Vtg,
               unsigned short* __restrict__ AO) {
    __shared__ unsigned short Ks[2][128 * 64];
    __shared__ unsigned short Vs[64 * 128];
    float* MRG = reinterpret_cast<float*>(Vs);   // merge overlay [2][64][18]

    const int n = blockIdx.x;               // 768 blocks
    const int x = n & 7, ii = n >> 3;       // XCD = n%8
    const int bh = ((ii >> 5) << 3) + x;    // 3 heads per XCD
    const int jp = ii & 31;                 // pair index
    const int t = threadIdx.x;
    const int w = t >> 6, lane = t & 63;
    const int lr = lane & 15, lg = lane >> 4;
    const int lgp = lg & 1;
    const int qh = w & 1, p = w >> 1;       // q-half, kv-half
    const size_t bhoff = (size_t)bh * (NS * NHD);
    const unsigned short* Kb = Kg + bhoff;
    const unsigned short* Vb = Vtg + bhoff;
    const int bswz = ((lg & 1) << 1) | (lg >> 1);
    const int ksr = lane >> 3, ksb = lane & 7;
    const int vsr = lane >> 4, vsb = lane & 15;
    const int bb = bh / NH, hh = bh - bb * NH;

#define STAGEK(buf, kvb)                                                        \
    {                                                                           \
        _Pragma("unroll")                                                       \
        for (int g = 0; g < 4; ++g) {                                           \
            const int row = g * 32 + w * 8 + ksr;                               \
            __builtin_amdgcn_global_load_lds(                                   \
                (const void*)(Kb + (size_t)((kvb) + row) * NHD + ((ksb ^ (row & 7)) * 8)), \
                (void*)(Ks[buf] + (g * 32 + w * 8) * 64), 16, 0, 0);            \
        }                                                                       \
    }
#define STAGEV(kvb)                                                             \
    {                                                                           \
        _Pragma("unroll")                                                       \
        for (int g = 0; g < 4; ++g) {                                           \
            const int d = g * 16 + w * 4 + vsr;                                 \
            __builtin_amdgcn_global_load_lds(                                   \
                (const void*)(Vb + (size_t)d * NS + (kvb) + ((vsb ^ (d & 7)) * 8)), \
                (void*)(Vs + (g * 16 + w * 4) * 128), 16, 0, 0);                \
        }                                                                       \
    }

#pragma unroll 1
    for (int mem = 0; mem < 2; ++mem) {
        const int qtile = mem ? jp : 63 - jp;
        const int q0 = qtile * 32;
        const int nr = qtile / 4 + 1;
        const int qrow = q0 + qh * 16 + lr;

        const unsigned short* Qp = Qg + bhoff + (size_t)qrow * NHD;
        const bf16x8 qB0 = *(const bf16x8*)(Qp + lg * 8);
        const bf16x8 qB1 = *(const bf16x8*)(Qp + 32 + lg * 8);

        float m_run = -1e30f, l_part = 0.f;
        f32x4 of[4];
#pragma unroll
        for (int f = 0; f < 4; ++f) of[f] = (f32x4){0.f, 0.f, 0.f, 0.f};

        STAGEK(0, 0);
        __syncthreads();                    // prologue K(0) visible
#pragma unroll 1
        for (int R = 0; R < nr; ++R) {
            STAGEV(R * 128);                              // V(R): used after B1
            if (R + 1 < nr) STAGEK((R + 1) & 1, (R + 1) * 128);
            const unsigned short* Kc = Ks[R & 1];
            const int kvw = R * 128 + p * 64;             // wave's kv base
            const bool active = kvw <= q0 + 31;

            f32x4 sf[4];
            bf16x8 pb[2];
            if (active) {
#pragma unroll
                for (int f = 0; f < 4; ++f) sf[f] = (f32x4){0.f, 0.f, 0.f, 0.f};
                __builtin_amdgcn_s_setprio(1);
#pragma unroll
                for (int f = 0; f < 4; ++f) {
                    const int krow = p * 64 + f * 16 + lr;
                    const bf16x8 a0 = *(const bf16x8*)&Kc[krow * 64 + ((lg ^ (krow & 7)) * 8)];
                    const bf16x8 a1 = *(const bf16x8*)&Kc[krow * 64 + (((4 + lg) ^ (krow & 7)) * 8)];
                    sf[f] = __builtin_amdgcn_mfma_f32_16x16x32_bf16(a0, qB0, sf[f], 0, 0, 0);
                    sf[f] = __builtin_amdgcn_mfma_f32_16x16x32_bf16(a1, qB1, sf[f], 0, 0, 0);
                }
                __builtin_amdgcn_s_setprio(0);

                const int rel = qrow - kvw;               // causal threshold
                if (rel < 63) {
#pragma unroll
                    for (int f = 0; f < 4; ++f)
#pragma unroll
                        for (int r = 0; r < 4; ++r)
                            if (f * 16 + lg * 4 + r > rel) sf[f][r] = -1e30f;
                }

                // ---- online softmax (exp2 domain), deferred-l ----
                float tm = -1e30f;
#pragma unroll
                for (int f = 0; f < 4; ++f)
                    tm = fmaxf(tm, fmaxf(fmaxf(sf[f][0], sf[f][1]), fmaxf(sf[f][2], sf[f][3])));
                tm = fmaxf(tm, __shfl_xor(tm, 16));
                tm = fmaxf(tm, __shfl_xor(tm, 32));
                if (!__all(tm <= m_run)) {
                    const float nm = fmaxf(m_run, tm);
                    const float corr = fexp2(m_run - nm);
                    m_run = nm;
                    l_part *= corr;
#pragma unroll
                    for (int f = 0; f < 4; ++f)
#pragma unroll
                        for (int r = 0; r < 4; ++r) of[f][r] *= corr;
                }
#pragma unroll
                for (int f = 0; f < 4; ++f)
#pragma unroll
                    for (int r = 0; r < 4; ++r) {
                        sf[f][r] = fexp2(sf[f][r] - m_run);
                        l_part += sf[f][r];
                    }

                // ---- pack P^T (sigma kv-permutation, xor16 partner swap) ----
#pragma unroll
                for (int c = 0; c < 2; ++c) {
                    const unsigned A0 = cvt_pk_bf16(sf[2 * c][0], sf[2 * c][1]);
                    const unsigned A1 = cvt_pk_bf16(sf[2 * c][2], sf[2 * c][3]);
                    const unsigned B0 = cvt_pk_bf16(sf[2 * c + 1][0], sf[2 * c + 1][1]);
                    const unsigned B1 = cvt_pk_bf16(sf[2 * c + 1][2], sf[2 * c + 1][3]);
                    const unsigned s0 = lgp ? A0 : B0;
                    const unsigned s1 = lgp ? A1 : B1;
                    const unsigned r0 = (unsigned)__shfl_xor((int)s0, 16);
                    const unsigned r1 = (unsigned)__shfl_xor((int)s1, 16);
                    const unsigned o0 = lgp ? B0 : A0;
                    const unsigned o1 = lgp ? B1 : A1;
                    u32x4 wvv;
                    wvv[0] = lgp ? r0 : o0;
                    wvv[1] = lgp ? r1 : o1;
                    wvv[2] = lgp ? o0 : r0;
                    wvv[3] = lgp ? o1 : r1;
                    pb[c] = __builtin_bit_cast(bf16x8, wvv);
                }
            }
            __syncthreads();                // B1: V(R) + K(R+1) visible
            if (active) {
                __builtin_amdgcn_s_setprio(1);
#pragma unroll
                for (int fA = 0; fA < 4; ++fA) {
                    const int drow = fA * 16 + lr;
#pragma unroll
                    for (int c = 0; c < 2; ++c) {
                        const int blk = p * 8 + 4 * c + bswz;
                        const bf16x8 va = *(const bf16x8*)&Vs[drow * 128 + ((blk ^ (drow & 7)) * 8)];
                        of[fA] = __builtin_amdgcn_mfma_f32_16x16x32_bf16(va, pb[c], of[fA], 0, 0, 0);
                    }
                }
                __builtin_amdgcn_s_setprio(0);
            }
            __syncthreads();                // B2: PV reads done; V buf free
        }

        // ---- cross-half merge (kv halves of same q rows) ----
        l_part += __shfl_xor(l_part, 16);
        l_part += __shfl_xor(l_part, 32);
        if (p == 1) {
            float* mr = &MRG[(qh * 64 + lane) * 18];
            mr[0] = m_run; mr[1] = l_part;
#pragma unroll
            for (int f = 0; f < 4; ++f)
#pragma unroll
                for (int r = 0; r < 4; ++r) mr[2 + f * 4 + r] = of[f][r];
        }
        __syncthreads();
        if (p == 0) {
            const float* mr = &MRG[(qh * 64 + lane) * 18];
            const float m1 = mr[0], l1 = mr[1];
            const float mm = fmaxf(m_run, m1);
            const float a0 = fexp2(m_run - mm);
            const float a1 = fexp2(m1 - mm);
            const float inv = 1.f / (l_part * a0 + l1 * a1);
            unsigned short* op = AO + ((size_t)(bb * NS + qrow)) * ND + hh * NHD;
#pragma unroll
            for (int fA = 0; fA < 4; ++fA) {
                ushort4 o4;
                o4.x = f2bf((of[fA][0] * a0 + mr[2 + fA * 4 + 0] * a1) * inv);
                o4.y = f2bf((of[fA][1] * a0 + mr[2 + fA * 4 + 1] * a1) * inv);
                o4.z = f2bf((of[fA][2] * a0 + mr[2 + fA * 4 + 2] * a1) * inv);
                o4.w = f2bf((of[fA][3] * a0 + mr[2 + fA * 4 + 3] * a1) * inv);
                *reinterpret_cast<ushort4*>(op + fA * 16 + lg * 4) = o4;
            }
        }
        __syncthreads();                    // MRG reads done before next member
    }
#undef STAGEK
#undef STAGEV
}

// ---------------------------------------------------------------------------
extern "C" void kernel_launch(void* const* d_in, const int* in_sizes, int n_in,
                              void* d_out, int out_size, void* d_ws, size_t ws_size,
                              hipStream_t stream) {
    const float* hs   = (const float*)d_in[0];
    const float* Wqkv = (const float*)d_in[1];
    const float* bqkv = (const float*)d_in[2];
    const float* Wout = (const float*)d_in[3];
    const float* bout = (const float*)d_in[4];
    float* out = (float*)d_out;

    char* wp = (char*)d_ws;
    unsigned short* hsb = (unsigned short*)wp; wp += (size_t)NM * ND * 2;
    unsigned short* W1t = (unsigned short*)wp; wp += (size_t)N3D * ND * 2;
    unsigned short* W2t = (unsigned short*)wp; wp += (size_t)ND * ND * 2;
    const size_t per = (size_t)NB * NH * NS * NHD;
    unsigned short* Qb  = (unsigned short*)wp; wp += per * 2;
    unsigned short* Kb  = (unsigned short*)wp; wp += per * 2;
    unsigned short* Vtb = (unsigned short*)wp; wp += per * 2;
    unsigned short* AOb = (unsigned short*)wp; wp += per * 2;

    prep<<<3072 + 1728 + 576, 256, 0, stream>>>(hs, hsb, Wqkv, W1t, Wout, W2t);

    gemm_k768<128, 96, 0><<<dim3(N3D / 96, NM / 128), 256, 0, stream>>>(
        hsb, W1t, bqkv, Qb, Kb, Vtb, nullptr);

    attn_mfma<<<768, 256, 0, stream>>>(Qb, Kb, Vtb, AOb);

    gemm_k768<64, 64, 1><<<dim3(ND / 64, NM / 64), 256, 0, stream>>>(
        AOb, W2t, bout, nullptr, nullptr, nullptr, out);
}